// Round 6
// baseline (7983.891 us; speedup 1.0000x reference)
//
#include <hip/hip_runtime.h>
#include <hip/hip_fp16.h>
#include <cstdint>
#include <cstddef>

typedef _Float16 f16x8 __attribute__((ext_vector_type(8)));
typedef float    f32x4 __attribute__((ext_vector_type(4)));

#define MFMA(A,B,C) __builtin_amdgcn_mfma_f32_16x16x32_f16((A),(B),(C),0,0,0)

// ---- problem constants ----
#define NRES  2048
#define DIN   32
#define DOUT  16
#define HDIM  128
#define BBATCH 64
#define TSTEPS 256
#define WCOLS 4224     // yp cols: 2048 res + 2048 att + 128 h1
#define NWORK 256      // worker blocks
#define NBLK  257      // + collector (2 blocks/CU co-residency guaranteed)

// ---- workspace layout (bytes) ----
#define OFF_WBIG  ((size_t)0)          // 4096*2048 f16  = 16,777,216 (res | att)
#define OFF_WH1   ((size_t)16777216)   // 128*2048 f16   -> 17,301,504
#define OFF_BIAS  ((size_t)17301504)   // 4224 f32       -> 17,318,400
#define OFF_WE2H  ((size_t)17318400)   // 128*128 f16    -> 17,351,168
#define OFF_WE3H  ((size_t)17351168)   // 2048*128 f16   -> 17,875,456
#define OFF_S16   ((size_t)17875456)   // 64*2048 f16    -> 18,137,600
#define OFF_YP    ((size_t)18137600)   // 64*4224 f32    -> 19,218,944
#define OFF_WINH  ((size_t)19219200)   // 2048*32 f16    -> 19,350,272
#define OFF_CNT   ((size_t)19350528)   // slots(256 u32, pad to 512) + wake(256*64B)

__device__ __forceinline__ float gelu_exact(float v) {
  return 0.5f * v * (1.0f + erff(v * 0.70710678118654752f));
}

// coalesced 16B write-through store (visible at device coherence point; L2 stays clean)
__device__ __forceinline__ void stg16(void* p, f32x4 v) {
  asm volatile("global_store_dwordx4 %0, %1, off sc0 sc1" :: "v"(p), "v"(v) : "memory");
}
// bypass loads: read straight from the coherence point (no L1/L2 allocation -> no staleness)
#define LDG16(dst, ptr) \
  asm volatile("global_load_dwordx4 %0, %1, off sc0 sc1" : "=v"(dst) : "v"(ptr) : "memory")
#define LDGF(dst, ptr) \
  asm volatile("global_load_dword %0, %1, off sc0 sc1" : "=v"(dst) : "v"(ptr) : "memory")

// ---------------- prep kernels (verified rounds 1-5) ----------------

__global__ void k_cast(const float* __restrict__ src, _Float16* __restrict__ dst, int n) {
  int i = blockIdx.x * blockDim.x + threadIdx.x;
  int stride = gridDim.x * blockDim.x;
  for (; i < n; i += stride) dst[i] = (_Float16)src[i];
}

__global__ void k_batt(const float* __restrict__ Wproj, const float* __restrict__ bv,
                       const float* __restrict__ bproj, float* __restrict__ bias_big) {
  int c = blockIdx.x, tid = threadIdx.x;
  float p = 0.f;
  for (int k = tid; k < NRES; k += 256) p += Wproj[(size_t)c * NRES + k] * bv[k];
  for (int m = 1; m < 64; m <<= 1) p += __shfl_xor(p, m);
  __shared__ float r4[4];
  if ((tid & 63) == 0) r4[tid >> 6] = p;
  __syncthreads();
  if (tid == 0) bias_big[2048 + c] = r4[0] + r4[1] + r4[2] + r4[3] + bproj[c];
}

__global__ void k_bh1(const float* __restrict__ We1, const float* __restrict__ be1,
                      float* __restrict__ bias_big) {
  int h = blockIdx.x, tid = threadIdx.x;
  float p = 0.f;
  for (int n = tid; n < NRES; n += 256) p += We1[(size_t)h * NRES + n] * bias_big[2048 + n];
  for (int m = 1; m < 64; m <<= 1) p += __shfl_xor(p, m);
  __shared__ float r4[4];
  if ((tid & 63) == 0) r4[tid >> 6] = p;
  __syncthreads();
  if (tid == 0) bias_big[4096 + h] = r4[0] + r4[1] + r4[2] + r4[3] + be1[h];
}

__global__ void __launch_bounds__(256) k_gemm1(const float* __restrict__ Wproj,
                                               const float* __restrict__ Wv,
                                               _Float16* __restrict__ wbig) {
  __shared__ _Float16 BT[64][40];
  const int kblock = blockIdx.x, cblock = blockIdx.y;
  const int tid = threadIdx.x, wv = tid >> 6, lane = tid & 63;
  const int l4 = lane >> 4, l15 = lane & 15;
  const int crow0 = cblock * 64 + wv * 16;
  f32x4 acc[4];
  f32x4 zero = {0.f, 0.f, 0.f, 0.f};
  for (int i = 0; i < 4; ++i) acc[i] = zero;

  for (int mc = 0; mc < 64; ++mc) {
    const int m0 = mc * 32;
    {
      int m = tid >> 3, kk = (tid & 7) * 8;
      const float* src = &Wv[(size_t)(m0 + m) * NRES + kblock * 64 + kk];
      float4 v0 = *(const float4*)src;
      float4 v1 = *(const float4*)(src + 4);
      float tmp[8] = {v0.x, v0.y, v0.z, v0.w, v1.x, v1.y, v1.z, v1.w};
      #pragma unroll
      for (int j = 0; j < 8; ++j) BT[kk + j][m] = (_Float16)tmp[j];
    }
    __syncthreads();
    const float* pa = &Wproj[(size_t)(crow0 + l15) * NRES + m0 + l4 * 8];
    float4 a0 = *(const float4*)pa;
    float4 a1 = *(const float4*)(pa + 4);
    f16x8 af;
    af[0]=(_Float16)a0.x; af[1]=(_Float16)a0.y; af[2]=(_Float16)a0.z; af[3]=(_Float16)a0.w;
    af[4]=(_Float16)a1.x; af[5]=(_Float16)a1.y; af[6]=(_Float16)a1.z; af[7]=(_Float16)a1.w;
    #pragma unroll
    for (int kt = 0; kt < 4; ++kt) {
      f16x8 bf = *(const f16x8*)&BT[kt * 16 + l15][l4 * 8];
      acc[kt] = MFMA(af, bf, acc[kt]);
    }
    __syncthreads();
  }
  #pragma unroll
  for (int kt = 0; kt < 4; ++kt)
    #pragma unroll
    for (int i = 0; i < 4; ++i) {
      int c = crow0 + l4 * 4 + i;
      int k = kblock * 64 + kt * 16 + l15;
      wbig[(size_t)(2048 + c) * NRES + k] = (_Float16)acc[kt][i];
    }
}

// W_h1 = We1 @ W_att -> wh1[0:128]
__global__ void __launch_bounds__(256) k_gemm2(const float* __restrict__ We1,
                                               const _Float16* __restrict__ wbig,
                                               _Float16* __restrict__ wh1) {
  __shared__ _Float16 BT[64][40];
  const int kblock = blockIdx.x, hblock = blockIdx.y;
  const int tid = threadIdx.x, wv = tid >> 6, lane = tid & 63;
  const int l4 = lane >> 4, l15 = lane & 15;
  const int hrow0 = hblock * 64 + wv * 16;
  f32x4 acc[4];
  f32x4 zero = {0.f, 0.f, 0.f, 0.f};
  for (int i = 0; i < 4; ++i) acc[i] = zero;

  for (int nc = 0; nc < 64; ++nc) {
    const int n0 = nc * 32;
    {
      int n = tid >> 3, kk = (tid & 7) * 8;
      f16x8 v = *(const f16x8*)&wbig[(size_t)(2048 + n0 + n) * NRES + kblock * 64 + kk];
      #pragma unroll
      for (int j = 0; j < 8; ++j) BT[kk + j][n] = v[j];
    }
    __syncthreads();
    const float* pa = &We1[(size_t)(hrow0 + l15) * NRES + n0 + l4 * 8];
    float4 a0 = *(const float4*)pa;
    float4 a1 = *(const float4*)(pa + 4);
    f16x8 af;
    af[0]=(_Float16)a0.x; af[1]=(_Float16)a0.y; af[2]=(_Float16)a0.z; af[3]=(_Float16)a0.w;
    af[4]=(_Float16)a1.x; af[5]=(_Float16)a1.y; af[6]=(_Float16)a1.z; af[7]=(_Float16)a1.w;
    #pragma unroll
    for (int kt = 0; kt < 4; ++kt) {
      f16x8 bf = *(const f16x8*)&BT[kt * 16 + l15][l4 * 8];
      acc[kt] = MFMA(af, bf, acc[kt]);
    }
    __syncthreads();
  }
  #pragma unroll
  for (int kt = 0; kt < 4; ++kt)
    #pragma unroll
    for (int i = 0; i < 4; ++i) {
      int h = hrow0 + l4 * 4 + i;
      int k = kblock * 64 + kt * 16 + l15;
      wh1[(size_t)h * NRES + k] = (_Float16)acc[kt][i];
    }
}

// ---------------- slot/wake barrier (no acquire: shared data is never cached) ----------------
__device__ __forceinline__ void gbar3(unsigned* slots, unsigned* wake, int b, unsigned phase) {
  asm volatile("s_waitcnt vmcnt(0)" ::: "memory");   // all sc1 stores acked at coherence point
  __syncthreads();
  if (threadIdx.x == 0) {
    __hip_atomic_store(slots + b, phase, __ATOMIC_RELAXED, __HIP_MEMORY_SCOPE_AGENT);
    unsigned spins = 0;
    while (__hip_atomic_load(wake + (size_t)b * 16, __ATOMIC_RELAXED, __HIP_MEMORY_SCOPE_AGENT) < phase) {
      __builtin_amdgcn_s_sleep(1);
      if (++spins > (1u << 20)) break;   // safety bail: wrong answer, not hang
    }
  }
  __syncthreads();
}

// ---------------- main persistent kernel ----------------

__global__ void __launch_bounds__(256, 2) k_main(
    const float* __restrict__ x,
    const float* __restrict__ ln_g, const float* __restrict__ ln_b,
    const float* __restrict__ be2v, const float* __restrict__ be3v,
    const float* __restrict__ w_mu, const float* __restrict__ w_rho,
    const float* __restrict__ b_mu, const float* __restrict__ b_rho,
    const float* __restrict__ w_eps, const float* __restrict__ b_eps,
    const _Float16* __restrict__ wbig, const _Float16* __restrict__ wh1,
    const float* __restrict__ bias_big,
    const _Float16* __restrict__ we2h, const _Float16* __restrict__ we3h,
    const _Float16* __restrict__ winh,
    _Float16* s16, float* yp,
    unsigned* cnt, float* __restrict__ out)
{
  const int b = blockIdx.x, tid = threadIdx.x;
  unsigned* slots = cnt;          // 256 u32 (region padded to 512)
  unsigned* wake  = cnt + 512;    // 256 lines, stride 16 u32 (64 B)

  // ===== collector block =====
  if (b == NWORK) {
    if (tid >= 64) return;
    for (unsigned p = 1; p <= 2u * TSTEPS; ++p) {
      unsigned spins = 0;
      for (;;) {
        bool ok = true;
        #pragma unroll
        for (int j = 0; j < 4; ++j) {
          unsigned v = __hip_atomic_load(slots + tid + j * 64, __ATOMIC_RELAXED, __HIP_MEMORY_SCOPE_AGENT);
          ok = ok && (v >= p);
        }
        if (__all((int)ok)) break;
        if (++spins > (1u << 19)) break;
        __builtin_amdgcn_s_sleep(1);
      }
      #pragma unroll
      for (int j = 0; j < 4; ++j)
        __hip_atomic_store(wake + (size_t)(tid + j * 64) * 16, p, __ATOMIC_RELAXED, __HIP_MEMORY_SCOPE_AGENT);
    }
    return;
  }

  const int wv = tid >> 6, lane = tid & 63;
  const int l4 = lane >> 4, l15 = lane & 15;

  // LDS total ~76.3 KB -> 2 blocks/CU fit (152.6 of 160 KB); collector co-resident
  __shared__ float    lds_red[4][64][17];    // S1 K-split reduce (17.4 KB)
  __shared__ _Float16 lds_w2[128][136];      // We2 resident (34.8 KB)
  __shared__ _Float16 lds_w3[32][136];       // We3 tile for this block's 32 cols (8.7 KB)
  __shared__ _Float16 lds_wi[32][40];        // W_in tile (2.5 KB)
  __shared__ float    lds_lnp[3][128];       // ln_g | ln_b | h1 bias (1.5 KB)
  __shared__ _Float16 lds_h1[16][136];       // gelu(LN(h1))
  __shared__ _Float16 lds_g2[16][136];       // gelu(h2)
  __shared__ _Float16 lds_x[16][40];         // x_t rows (f16)
  __shared__ _Float16 lds_ns[16][40];        // new-state bounce for coalesced store

  // ---- S1: strip b (16 cols, full K, 4-wave K-split); blocks 0..7 also one h1 strip
  const bool dual = (b < 8);
  f16x8 Bf[16], Bf2[16];
  #pragma unroll
  for (int ks = 0; ks < 16; ++ks)
    Bf[ks] = *(const f16x8*)&wbig[(size_t)(b * 16 + l15) * NRES + wv * 512 + ks * 32 + l4 * 8];
  if (dual) {
    #pragma unroll
    for (int ks = 0; ks < 16; ++ks)
      Bf2[ks] = *(const f16x8*)&wh1[(size_t)(b * 16 + l15) * NRES + wv * 512 + ks * 32 + l4 * 8];
  }

  // ---- S3 identity: all workers own 16 rows x 32 cols ----
  const int R0 = (b >> 6) * 16, C0 = (b & 63) * 32;
  const int mycol = C0 + wv * 16 + l15;      // waves 0,1 update these cols
  const int lcol  = wv * 16 + l15;           // local col in [0,32) for lds_w3/lds_wi

  float be2r[2];
  #pragma unroll
  for (int ct = 0; ct < 2; ++ct) be2r[ct] = be2v[(wv * 2 + ct) * 16 + l15];
  float be3r = 0.f, battr = 0.f;
  if (wv < 2) {
    be3r  = be3v[mycol];
    battr = bias_big[2048 + mycol];
  }

  { // stage We2 (128x128), We3 tile (32x128), W_in tile (32x32), LN params into LDS
    int row = tid >> 1, half = tid & 1;
    #pragma unroll
    for (int j = 0; j < 8; ++j)
      *(f16x8*)&lds_w2[row][half * 64 + j * 8] =
          *(const f16x8*)&we2h[(size_t)row * HDIM + half * 64 + j * 8];
    for (int idx = tid; idx < 32 * 16; idx += 256) {
      int c = idx >> 4, kk8 = (idx & 15) * 8;
      *(f16x8*)&lds_w3[c][kk8] = *(const f16x8*)&we3h[(size_t)(C0 + c) * HDIM + kk8];
    }
    for (int idx = tid; idx < 32 * 4; idx += 256) {
      int c = idx >> 2, kk8 = (idx & 3) * 8;
      *(f16x8*)&lds_wi[c][kk8] = *(const f16x8*)&winh[(size_t)(C0 + c) * DIN + kk8];
    }
    if (tid < 128) {
      lds_lnp[0][tid] = ln_g[tid];
      lds_lnp[1][tid] = ln_b[tid];
      lds_lnp[2][tid] = bias_big[4096 + tid];
    }
  }
  __syncthreads();

  // t-invariant S1 row pointers (wave's K-quarter)
  const _Float16* q0 = s16 + (size_t)(l15) * NRES + wv * 512 + l4 * 8;
  const _Float16* q1 = q0 + 16 * NRES;
  const _Float16* q2 = q0 + 32 * NRES;
  const _Float16* q3 = q0 + 48 * NRES;

  const f32x4 zero = {0.f, 0.f, 0.f, 0.f};
  unsigned phase = 0;

  // consumer mapping for coalesced yp store: row cr = tid>>2, 4-col chunk cch = tid&3
  const int cr  = tid >> 2, cch = tid & 3;
  const int rqi = (cr >> 4) * 4 + (cr & 3);       // acc element index q*4+i
  const int pl4 = (cr >> 2) & 3;                  // producer l4

  for (int t = 0; t < TSTEPS; ++t) {
    // ===== S1: Y[:, strips] = s @ W.T, bypass loads, depth-3 pipelined =====
    f32x4 a0 = zero, a1 = zero, a2 = zero, a3 = zero;
    f32x4 e0 = zero, e1 = zero, e2 = zero, e3 = zero;
    {
      f16x8 A[3][4];
      #pragma unroll
      for (int c = 0; c < 3; ++c) {       // prologue: chunks 0..2 (12 loads in flight)
        LDG16(A[c][0], q0 + c * 32);
        LDG16(A[c][1], q1 + c * 32);
        LDG16(A[c][2], q2 + c * 32);
        LDG16(A[c][3], q3 + c * 32);
      }
      #pragma unroll
      for (int ks = 0; ks < 16; ++ks) {
        if (ks <= 13)      { asm volatile("s_waitcnt vmcnt(8)" ::: "memory"); }
        else if (ks == 14) { asm volatile("s_waitcnt vmcnt(4)" ::: "memory"); }
        else               { asm volatile("s_waitcnt vmcnt(0)" ::: "memory"); }
        __builtin_amdgcn_sched_barrier(0);
        const int sl = ks % 3;
        a0 = MFMA(A[sl][0], Bf[ks], a0);
        a1 = MFMA(A[sl][1], Bf[ks], a1);
        a2 = MFMA(A[sl][2], Bf[ks], a2);
        a3 = MFMA(A[sl][3], Bf[ks], a3);
        if (dual) {
          e0 = MFMA(A[sl][0], Bf2[ks], e0);
          e1 = MFMA(A[sl][1], Bf2[ks], e1);
          e2 = MFMA(A[sl][2], Bf2[ks], e2);
          e3 = MFMA(A[sl][3], Bf2[ks], e3);
        }
        if (ks + 3 < 16) {
          LDG16(A[sl][0], q0 + (ks + 3) * 32);
          LDG16(A[sl][1], q1 + (ks + 3) * 32);
          LDG16(A[sl][2], q2 + (ks + 3) * 32);
          LDG16(A[sl][3], q3 + (ks + 3) * 32);
        }
      }
    }
    #pragma unroll
    for (int i = 0; i < 4; ++i) {
      lds_red[wv][lane][0 + i]  = a0[i];
      lds_red[wv][lane][4 + i]  = a1[i];
      lds_red[wv][lane][8 + i]  = a2[i];
      lds_red[wv][lane][12 + i] = a3[i];
    }
    __syncthreads();
    { // coalesced reduce+store: thread -> (row cr, cols cch*4..cch*4+3)
      f32x4 v;
      #pragma unroll
      for (int c = 0; c < 4; ++c) {
        int pl = pl4 * 16 + cch * 4 + c;
        v[c] = lds_red[0][pl][rqi] + lds_red[1][pl][rqi]
             + lds_red[2][pl][rqi] + lds_red[3][pl][rqi];
      }
      stg16(&yp[(size_t)cr * WCOLS + b * 16 + cch * 4], v);
    }
    if (dual) {  // second pass through the reduce buffer for the h1 strip
      __syncthreads();
      #pragma unroll
      for (int i = 0; i < 4; ++i) {
        lds_red[wv][lane][0 + i]  = e0[i];
        lds_red[wv][lane][4 + i]  = e1[i];
        lds_red[wv][lane][8 + i]  = e2[i];
        lds_red[wv][lane][12 + i] = e3[i];
      }
      __syncthreads();
      f32x4 v2;
      #pragma unroll
      for (int c = 0; c < 4; ++c) {
        int pl = pl4 * 16 + cch * 4 + c;
        v2[c] = lds_red[0][pl][rqi] + lds_red[1][pl][rqi]
              + lds_red[2][pl][rqi] + lds_red[3][pl][rqi];
      }
      stg16(&yp[(size_t)cr * WCOLS + 4096 + b * 16 + cch * 4], v2);
    }
    ++phase;
    gbar3(slots, wake, b, phase);

    // ===== S3: LN -> GELU -> We2 -> GELU -> We3 -> state update =====
    { // stage x_t (16 rows x 32) as f16 (cached: x is read-only input)
      int xr = tid >> 4, k0 = (tid & 15) * 2;
      const float* xs = &x[((size_t)(R0 + xr) * TSTEPS + t) * DIN + k0];
      lds_x[xr][k0]     = (_Float16)xs[0];
      lds_x[xr][k0 + 1] = (_Float16)xs[1];
    }
    // h1 via bypass loads, LayerNorm over 128, exact GELU (row lr = wv*4+l4)
    const int lr = wv * 4 + l4;
    float hv[8];
    {
      const float* hp = &yp[(size_t)(R0 + lr) * WCOLS + 4096 + l15];
      #pragma unroll
      for (int jj = 0; jj < 8; ++jj) LDGF(hv[jj], hp + 16 * jj);
      asm volatile("s_waitcnt vmcnt(0)" ::: "memory");
      __builtin_amdgcn_sched_barrier(0);
    }
    float h1v[8], s1 = 0.f, s2 = 0.f;
    #pragma unroll
    for (int jj = 0; jj < 8; ++jj) {
      float v = hv[jj] + lds_lnp[2][l15 + 16 * jj];
      h1v[jj] = v; s1 += v; s2 += v * v;
    }
    #pragma unroll
    for (int m = 1; m < 16; m <<= 1) { s1 += __shfl_xor(s1, m); s2 += __shfl_xor(s2, m); }
    const float mu = s1 * (1.f / 128.f);
    const float var = s2 * (1.f / 128.f) - mu * mu;
    const float rs = rsqrtf(var + 1e-5f);
    #pragma unroll
    for (int jj = 0; jj < 8; ++jj) {
      int j = l15 + 16 * jj;
      float hn = (h1v[jj] - mu) * rs * lds_lnp[0][j] + lds_lnp[1][j];
      lds_h1[lr][j] = (_Float16)gelu_exact(hn);
    }
    __syncthreads();
    // h2 = gelu(h1g @ We2^T + be2): wave wv does col-tiles wv*2, wv*2+1
    f32x4 c0 = zero, c1 = zero;
    #pragma unroll
    for (int ks = 0; ks < 4; ++ks) {
      f16x8 af = *(const f16x8*)&lds_h1[l15][ks * 32 + l4 * 8];
      f16x8 b0 = *(const f16x8*)&lds_w2[(wv * 2 + 0) * 16 + l15][ks * 32 + l4 * 8];
      f16x8 b1 = *(const f16x8*)&lds_w2[(wv * 2 + 1) * 16 + l15][ks * 32 + l4 * 8];
      c0 = MFMA(af, b0, c0);
      c1 = MFMA(af, b1, c1);
    }
    #pragma unroll
    for (int i = 0; i < 4; ++i) {
      int rr = l4 * 4 + i;
      lds_g2[rr][(wv * 2 + 0) * 16 + l15] = (_Float16)gelu_exact(c0[i] + be2r[0]);
      lds_g2[rr][(wv * 2 + 1) * 16 + l15] = (_Float16)gelu_exact(c1[i] + be2r[1]);
    }
    __syncthreads();
    // phys + input-term + state update: waves 0,1 own cols C0..C0+31
    if (wv < 2) {
      float sattv[4], rrvv[4];
      #pragma unroll
      for (int i = 0; i < 4; ++i) {
        const float* pa_ = &yp[(size_t)(R0 + l4 * 4 + i) * WCOLS + 2048 + mycol];
        const float* pb_ = &yp[(size_t)(R0 + l4 * 4 + i) * WCOLS + mycol];
        LDGF(sattv[i], pa_);
        LDGF(rrvv[i], pb_);
      }
      f32x4 accp = zero;
      #pragma unroll
      for (int ks = 0; ks < 4; ++ks) {
        f16x8 af = *(const f16x8*)&lds_g2[l15][ks * 32 + l4 * 8];
        f16x8 w3 = *(const f16x8*)&lds_w3[lcol][ks * 32 + l4 * 8];
        accp = MFMA(af, w3, accp);
      }
      f16x8 ax = *(const f16x8*)&lds_x[l15][l4 * 8];
      f16x8 wi = *(const f16x8*)&lds_wi[lcol][l4 * 8];
      f32x4 acci = MFMA(ax, wi, zero);
      asm volatile("s_waitcnt vmcnt(0)" ::: "memory");
      __builtin_amdgcn_sched_barrier(0);
      #pragma unroll
      for (int i = 0; i < 4; ++i) {
        int r2 = l4 * 4 + i;
        float satt = sattv[i] + battr;
        float ns = 0.7f * satt + 0.3f * tanhf(acci[i] + rrvv[i] + accp[i] + be3r);
        lds_ns[r2][wv * 16 + l15] = (_Float16)ns;
      }
    }
    __syncthreads();
    if (tid < 64) {  // coalesced s16 store: row r, 8-col chunk ch (16B each, 64B/row)
      int r = tid >> 2, ch = tid & 3;
      f16x8 v = *(const f16x8*)&lds_ns[r][ch * 8];
      stg16(&s16[(size_t)(R0 + r) * NRES + C0 + ch * 8], __builtin_bit_cast(f32x4, v));
    }
    ++phase;
    gbar3(slots, wake, b, phase);
  }

  // ---- Bayesian output head (blocks 0..63; bypass reads of final state) ----
  if (b < BBATCH) {
    float* red = &lds_red[0][0][0];
    int o = tid >> 4, sg = tid & 15;
    f16x8 sbuf[16];
    {
      const _Float16* sp = &s16[(size_t)b * NRES + sg * 128];
      #pragma unroll
      for (int jj = 0; jj < 16; ++jj) LDG16(sbuf[jj], sp + jj * 8);
      asm volatile("s_waitcnt vmcnt(0)" ::: "memory");
      __builtin_amdgcn_sched_barrier(0);
    }
    float p = 0.f;
    #pragma unroll
    for (int jj = 0; jj < 16; ++jj) {
      #pragma unroll
      for (int k = 0; k < 8; ++k) {
        int n = sg * 128 + jj * 8 + k;
        float sv = (float)sbuf[jj][k];
        float w = w_mu[(size_t)o * NRES + n]
                + log1pf(expf(w_rho[(size_t)o * NRES + n])) * w_eps[(size_t)o * NRES + n];
        p += sv * w;
      }
    }
    red[o * 17 + sg] = p;
    __syncthreads();
    if (tid < DOUT) {
      float sum = 0.f;
      for (int q = 0; q < 16; ++q) sum += red[tid * 17 + q];
      float bs = b_mu[tid] + log1pf(expf(b_rho[tid])) * b_eps[tid];
      out[b * DOUT + tid] = sum + bs;
    }
  }
}

// ---------------- host ----------------

extern "C" void kernel_launch(void* const* d_in, const int* in_sizes, int n_in,
                              void* d_out, int out_size, void* d_ws, size_t ws_size,
                              hipStream_t stream) {
  (void)in_sizes; (void)n_in; (void)out_size; (void)ws_size;
  const float* x     = (const float*)d_in[0];
  const float* W_in  = (const float*)d_in[1];
  const float* W_res = (const float*)d_in[2];
  const float* Wv    = (const float*)d_in[3];
  const float* bv    = (const float*)d_in[4];
  const float* Wproj = (const float*)d_in[5];
  const float* bproj = (const float*)d_in[6];
  const float* We1   = (const float*)d_in[7];
  const float* be1   = (const float*)d_in[8];
  const float* ln_g  = (const float*)d_in[9];
  const float* ln_b  = (const float*)d_in[10];
  const float* We2   = (const float*)d_in[11];
  const float* be2   = (const float*)d_in[12];
  const float* We3   = (const float*)d_in[13];
  const float* be3   = (const float*)d_in[14];
  const float* w_mu  = (const float*)d_in[15];
  const float* w_rho = (const float*)d_in[16];
  const float* b_mu  = (const float*)d_in[17];
  const float* b_rho = (const float*)d_in[18];
  const float* w_eps = (const float*)d_in[19];
  const float* b_eps = (const float*)d_in[20];
  float* out = (float*)d_out;

  char* ws = (char*)d_ws;
  _Float16* wbig     = (_Float16*)(ws + OFF_WBIG);
  _Float16* wh1      = (_Float16*)(ws + OFF_WH1);
  float*    bias_big = (float*)(ws + OFF_BIAS);
  _Float16* we2h     = (_Float16*)(ws + OFF_WE2H);
  _Float16* we3h     = (_Float16*)(ws + OFF_WE3H);
  _Float16* s16      = (_Float16*)(ws + OFF_S16);
  float*    yp       = (float*)(ws + OFF_YP);
  _Float16* winh     = (_Float16*)(ws + OFF_WINH);
  unsigned* cnt      = (unsigned*)(ws + OFF_CNT);

  hipMemsetAsync(bias_big, 0, WCOLS * sizeof(float), stream);
  hipMemsetAsync(s16, 0, (size_t)BBATCH * NRES * sizeof(_Float16), stream);
  hipMemsetAsync(cnt, 0, 512 * 4 + 256 * 64, stream);   // slots + wake lines

  k_cast<<<4096, 256, 0, stream>>>(W_res, wbig, NRES * NRES);                  // wbig[0:2048]
  k_cast<<<64,   256, 0, stream>>>(We2, we2h, HDIM * HDIM);
  k_cast<<<1024, 256, 0, stream>>>(We3, we3h, NRES * HDIM);
  k_cast<<<256,  256, 0, stream>>>(W_in, winh, NRES * DIN);
  k_batt<<<NRES, 256, 0, stream>>>(Wproj, bv, bproj, bias_big);
  k_gemm1<<<dim3(32, 32), 256, 0, stream>>>(Wproj, Wv, wbig);                  // wbig[2048:4096]
  k_bh1<<<HDIM, 256, 0, stream>>>(We1, be1, bias_big);
  k_gemm2<<<dim3(32, 2), 256, 0, stream>>>(We1, wbig, wh1);                    // wh1[0:128]

  k_main<<<NBLK, 256, 0, stream>>>(x, ln_g, ln_b, be2, be3,
                                   w_mu, w_rho, b_mu, b_rho, w_eps, b_eps,
                                   wbig, wh1, bias_big, we2h, we3h, winh, s16, yp, cnt, out);
}